// Round 10
// baseline (133.484 us; speedup 1.0000x reference)
//
#include <hip/hip_runtime.h>

#define OUT_N 5
#define TOTAL_NODES 65024
#define ROOTS_OFF (TOTAL_NODES * OUT_N)

typedef __attribute__((ext_vector_type(8))) short bf16x8;
typedef __attribute__((ext_vector_type(4))) float f32x4;
typedef __attribute__((ext_vector_type(8))) unsigned short ushort8v;
typedef __attribute__((ext_vector_type(4))) unsigned int uint4v;

static __device__ __forceinline__ unsigned short f2bf(float f) {
    union { float f; unsigned int i; } v; v.f = f;
    unsigned int r = v.i + 0x7fff + ((v.i >> 16) & 1);   // RNE
    return (unsigned short)(r >> 16);
}

// fp32 node row R (128 B), chunk c (0..7, 4 floats): chunk ROTATED by R.
// Breaks 128B-stride bank alignment AND implements the hi-rotation trick.
static __device__ __forceinline__ int naddr32(int R, int c) {
    return R * 128 + (((c + R) & 7) << 4);
}
static __device__ __forceinline__ void store_h32(char* smem, int R, int col, float v) {
    *(float*)(smem + naddr32(R, col >> 2) + (col & 3) * 4) = v;
}

// ---------------------------------------------------------------------------
// bprep: symmetric-pair B table (K=2144 -> 67 ksteps), MFMA-fragment order.
// Separate kernel: its output crosses blocks; kernel boundary = coherence.
// ---------------------------------------------------------------------------
__global__ __launch_bounds__(64) void bprep_kernel(
    const float* __restrict__ V, const float* __restrict__ W,
    unsigned short* __restrict__ B)
{
    int t = blockIdx.x * 64 + threadIdx.x;
    if (t >= 8576) return;                   // 67*2*64
    int ks = t >> 7, sub = t & 127;
    int n = sub >> 6, lane = sub & 63;
    int hi = lane >> 4, l15 = lane & 15;
    int k = n * 16 + l15;
    const float* Vk = V + (size_t)k * 4096;
    ushort8v o;
    #pragma unroll
    for (int i = 0; i < 8; ++i) {
        int r5 = hi * 8 + i;
        float val;
        if (ks < 2)        { int j = 32 * ks + r5; val = Vk[j * 64 + j]; }
        else if (ks < 64)  { int d = ks >> 1; int j = 32 * (ks & 1) + r5; int l = (j + d) & 63;
                             val = Vk[j * 64 + l] + Vk[l * 64 + j]; }
        else if (ks == 64) { int j = r5; val = Vk[j * 64 + j + 32] + Vk[(j + 32) * 64 + j]; }
        else               { int j = (ks == 65) ? r5 : (32 + r5); val = W[j * 32 + k]; }
        o[i] = f2bf(val);
    }
    *(ushort8v*)(B + (size_t)t * 8) = o;
}

// ---------------------------------------------------------------------------
// crot[x] = c[(x + hi*8) & 63], fp32, from rotated-chunk LDS rows Rc, Rc+1.
// ---------------------------------------------------------------------------
static __device__ __forceinline__ void load_crot32(
    const char* nodes, int Rc, int hi, float* crot)
{
    #pragma unroll
    for (int t = 0; t < 16; ++t) {
        int m = (hi * 2 + t) & 15;           // chunk in 64-float c-space
        int row = Rc + (m >> 3), c4 = m & 7;
        f32x4 v = *(const f32x4*)(nodes + naddr32(row, c4));
        #pragma unroll
        for (int e = 0; e < 4; ++e) crot[t * 4 + e] = v[e];
    }
}

// ---------------------------------------------------------------------------
// Compile-time k-range, BOTH ntiles per wave (one A-build -> 2 MFMAs).
// ---------------------------------------------------------------------------
template<int K0, int K1>
static __device__ __forceinline__ void run2_k(
    const unsigned short* __restrict__ Bg, const float* crot,
    int lane, f32x4& a0, f32x4& a1)
{
    const char* bp = (const char*)Bg + lane * 16;
    #pragma unroll
    for (int ks = K0; ks < K1; ++ks) {
        uint4v aw;
        #pragma unroll
        for (int q = 0; q < 4; ++q) {
            int i0 = 2 * q, i1 = 2 * q + 1;
            float p0, p1;
            if (ks < 2)       { p0 = crot[32*ks+i0] * crot[32*ks+i0];
                                p1 = crot[32*ks+i1] * crot[32*ks+i1]; }
            else if (ks < 64) { const int bse = 32 * (ks & 1), d = ks >> 1;
                                p0 = crot[bse+i0] * crot[(bse+i0+d)&63];
                                p1 = crot[bse+i1] * crot[(bse+i1+d)&63]; }
            else if (ks == 64){ p0 = crot[i0] * crot[32+i0];
                                p1 = crot[i1] * crot[32+i1]; }
            else if (ks == 65){ p0 = crot[i0];    p1 = crot[i1]; }
            else              { p0 = crot[32+i0]; p1 = crot[32+i1]; }
            unsigned int pk;
            asm("v_cvt_pk_bf16_f32 %0, %1, %2" : "=v"(pk) : "v"(p0), "v"(p1));
            aw[q] = pk;
        }
        bf16x8 afr = __builtin_bit_cast(bf16x8, aw);
        bf16x8 b0 = *(const bf16x8*)(bp + (ks << 11));
        bf16x8 b1 = *(const bf16x8*)(bp + (ks << 11) + 1024);
        a0 = __builtin_amdgcn_mfma_f32_16x16x32_bf16(afr, b0, a0, 0, 0, 0);
        a1 = __builtin_amdgcn_mfma_f32_16x16x32_bf16(afr, b1, a1, 0, 0, 0);
    }
}

// log_softmax from 32 fp32 h values in rotated LDS row R -> out[g*5..]
static __device__ __forceinline__ void node_logits32(
    const char* smem, int R, const float* __restrict__ Wout_w,
    const float* __restrict__ Wout_b, float* __restrict__ out, size_t g)
{
    float h[32];
    #pragma unroll
    for (int c = 0; c < 8; ++c) {
        f32x4 v = *(const f32x4*)(smem + naddr32(R, c));
        #pragma unroll
        for (int e = 0; e < 4; ++e) h[c * 4 + e] = v[e];
    }
    float lg[OUT_N];
    #pragma unroll
    for (int o = 0; o < OUT_N; ++o) {
        const float* w = Wout_w + o * 32;
        float s = 0.f;
        #pragma unroll
        for (int x = 0; x < 32; ++x) s = fmaf(w[x], h[x], s);
        lg[o] = s + Wout_b[o];
    }
    float m = lg[0];
    #pragma unroll
    for (int o = 1; o < OUT_N; ++o) m = fmaxf(m, lg[o]);
    float sum = 0.f;
    #pragma unroll
    for (int o = 0; o < OUT_N; ++o) sum += expf(lg[o] - m);
    float lse = m + logf(sum);
    #pragma unroll
    for (int o = 0; o < OUT_N; ++o) out[g * OUT_N + o] = lg[o] - lse;
}

// ---------------------------------------------------------------------------
// One level tile: 4 waves = splitK4, both ntiles per wave. RPT = valid rows.
// childb/outb are runtime row bases (keeps template instantiations at 5).
// ---------------------------------------------------------------------------
constexpr int SCR = 12288;   // scratch base (3 slots x 2 KB)

template<int RPT, bool ROOT>
static __device__ __forceinline__ void level_run(
    char* smem, const unsigned short* __restrict__ Bg,
    const float* __restrict__ bias, float* __restrict__ roots,
    int bid, int lane, int u, int childb, int outb)
{
    const int l15 = lane & 15, hi = lane >> 4;
    int rc = (RPT >= 16) ? l15 : ((l15 < RPT) ? l15 : 0);
    float crot[64];
    load_crot32(smem, childb + 2 * rc, hi, crot);

    f32x4 a0 = {0.f,0.f,0.f,0.f}, a1 = {0.f,0.f,0.f,0.f};
    switch (u) {
        case 0:  run2_k< 0, 17>(Bg, crot, lane, a0, a1); break;
        case 1:  run2_k<17, 34>(Bg, crot, lane, a0, a1); break;
        case 2:  run2_k<34, 50>(Bg, crot, lane, a0, a1); break;
        default: run2_k<50, 67>(Bg, crot, lane, a0, a1); break;
    }
    if (u > 0) {
        char* sp = smem + SCR + (u - 1) * 2048 + lane * 32;
        *(f32x4*)sp = a0; *((f32x4*)sp + 1) = a1;
    }
    __syncthreads();
    if (u == 0) {
        #pragma unroll
        for (int v2 = 0; v2 < 3; ++v2) {
            const char* sp = smem + SCR + v2 * 2048 + lane * 32;
            a0 += *(const f32x4*)sp;
            a1 += *((const f32x4*)sp + 1);
        }
        float bk0 = bias[l15], bk1 = bias[16 + l15];
        #pragma unroll
        for (int r4 = 0; r4 < 4; ++r4) {
            int row = hi * 4 + r4;
            if (row < RPT) {
                float h0 = tanhf(a0[r4] + bk0), h1v = tanhf(a1[r4] + bk1);
                store_h32(smem, outb + row, l15, h0);
                store_h32(smem, outb + row, 16 + l15, h1v);
                if (ROOT) {
                    roots[(size_t)bid * 32 + l15]      = h0;
                    roots[(size_t)bid * 32 + 16 + l15] = h1v;
                }
            }
        }
    }
    __syncthreads();
}

// ---------------------------------------------------------------------------
// Fused tree kernel: block = ONE tree (512 blocks x 256 thr).
// Phase 1: 2 L1 tiles (leaf gather + exact leaf logits + level1 -> LDS only).
// Phase 2: L2..L6 + all logits + roots. h1 NEVER touches global memory.
// LDS rows: nodes 0..62 (h1 0..31, L2 32..47, L3 48..55, L4 56..59,
// L5 60..61, L6 62), leaf staging 64..95. Scratch 3x2KB @12288.
// ---------------------------------------------------------------------------
__global__ __launch_bounds__(256, 4) void tree_kernel(
    const int* __restrict__ word_ids, const float* __restrict__ embed,
    const unsigned short* __restrict__ Bg, const float* __restrict__ bias,
    const float* __restrict__ Wout_w, const float* __restrict__ Wout_b,
    float* __restrict__ out)
{
    __shared__ char smem[12288 + 6144];
    const int tid = threadIdx.x, lane = tid & 63;
    const int u = tid >> 6;
    const int bid = blockIdx.x;
    float* roots = out + ROOTS_OFF;

    // ---- phase 1: two 16-node L1 tiles ------------------------------------
    #pragma unroll
    for (int p = 0; p < 2; ++p) {
        {   // stage 32 leaf rows fp32 + exact leaf logits
            int rr = tid >> 3, q4 = tid & 7;       // 32 rows x 8 chunks
            int leaf = (bid * 2 + p) * 32 + rr;
            int wid = word_ids[leaf];
            f32x4 v = ((const f32x4*)(embed + (size_t)wid * 32))[q4];
            *(f32x4*)(smem + naddr32(64 + rr, q4)) = v;

            float lg[OUT_N];
            #pragma unroll
            for (int o = 0; o < OUT_N; ++o) {
                const float* w = Wout_w + o * 32 + q4 * 4;
                lg[o] = w[0]*v[0] + w[1]*v[1] + w[2]*v[2] + w[3]*v[3];
            }
            #pragma unroll
            for (int o = 0; o < OUT_N; ++o) {
                lg[o] += __shfl_xor(lg[o], 1, 64);
                lg[o] += __shfl_xor(lg[o], 2, 64);
                lg[o] += __shfl_xor(lg[o], 4, 64);
            }
            if (q4 == 0) {
                #pragma unroll
                for (int o = 0; o < OUT_N; ++o) lg[o] += Wout_b[o];
                float m = lg[0];
                #pragma unroll
                for (int o = 1; o < OUT_N; ++o) m = fmaxf(m, lg[o]);
                float sum = 0.f;
                #pragma unroll
                for (int o = 0; o < OUT_N; ++o) sum += expf(lg[o] - m);
                float lse = m + logf(sum);
                #pragma unroll
                for (int o = 0; o < OUT_N; ++o) out[(size_t)leaf * OUT_N + o] = lg[o] - lse;
            }
        }
        __syncthreads();
        if (p == 0) level_run<16, false>(smem, Bg, bias, roots, bid, lane, u, 64, 0);
        else        level_run<16, false>(smem, Bg, bias, roots, bid, lane, u, 64, 16);
    }

    // ---- h1 logits (rows 0..31 complete after level_run's trailing sync) --
    if (tid < 32)
        node_logits32(smem, tid, Wout_w, Wout_b, out,
                      (size_t)32768 + (size_t)bid * 32 + tid);

    // ---- phase 2: L2..L6 (children rows -> output rows, all in LDS) -------
    level_run<16, false>(smem, Bg, bias, roots, bid, lane, u,  0, 32);  // L2
    level_run< 8, false>(smem, Bg, bias, roots, bid, lane, u, 32, 48);  // L3
    level_run< 4, false>(smem, Bg, bias, roots, bid, lane, u, 48, 56);  // L4
    level_run< 2, false>(smem, Bg, bias, roots, bid, lane, u, 56, 60);  // L5
    level_run< 1, true >(smem, Bg, bias, roots, bid, lane, u, 60, 62);  // L6

    // ---- logits for the tree's 31 internal L2..L6 nodes -------------------
    if (tid < 31) {
        int rr = tid; int R; size_t g;
        if (rr < 16)      { R = 32 + rr;        g = 49152 + (size_t)bid * 16 + rr; }
        else if (rr < 24) { R = 48 + (rr - 16); g = 57344 + (size_t)bid * 8  + (rr - 16); }
        else if (rr < 28) { R = 56 + (rr - 24); g = 61440 + (size_t)bid * 4  + (rr - 24); }
        else if (rr < 30) { R = 60 + (rr - 28); g = 63488 + (size_t)bid * 2  + (rr - 28); }
        else              { R = 62;             g = 64512 + (size_t)bid; }
        node_logits32(smem, R, Wout_w, Wout_b, out, g);
    }
}

// ---------------------------------------------------------------------------
extern "C" void kernel_launch(void* const* d_in, const int* in_sizes, int n_in,
                              void* d_out, int out_size, void* d_ws, size_t ws_size,
                              hipStream_t stream)
{
    const int*   word_ids = (const int*)  d_in[0];
    const float* embed    = (const float*)d_in[1];
    const float* V        = (const float*)d_in[2];
    const float* W        = (const float*)d_in[3];
    const float* bvec     = (const float*)d_in[4];
    const float* Wout_w   = (const float*)d_in[5];
    const float* Wout_b   = (const float*)d_in[6];
    float* out = (float*)d_out;

    unsigned short* Bfrag = (unsigned short*)d_ws;   // 137,216 B

    bprep_kernel<<<134, 64, 0, stream>>>(V, W, Bfrag);
    tree_kernel<<<512, 256, 0, stream>>>(word_ids, embed, Bfrag, bvec,
                                         Wout_w, Wout_b, out);
}

// Round 11
// 86.587 us; speedup vs baseline: 1.5416x; 1.5416x over previous
//
#include <hip/hip_runtime.h>

#define OUT_N 5
#define TOTAL_NODES 65024
#define ROOTS_OFF (TOTAL_NODES * OUT_N)

typedef __attribute__((ext_vector_type(8))) short bf16x8;
typedef __attribute__((ext_vector_type(4))) float f32x4;
typedef __attribute__((ext_vector_type(8))) unsigned short ushort8v;
typedef __attribute__((ext_vector_type(4))) unsigned int uint4v;

static __device__ __forceinline__ unsigned short f2bf(float f) {
    union { float f; unsigned int i; } v; v.f = f;
    unsigned int r = v.i + 0x7fff + ((v.i >> 16) & 1);   // RNE
    return (unsigned short)(r >> 16);
}

// fp32 node row R (128 B), logical chunk c (0..7): physical chunk rotated by
// (R + R>>1) — odd l15-coefficient spreads 2*l15 rows over all 8 rotations
// (old (c+R)&7 with even R gave 4-way conflicts; m136: 2-way is free).
static __device__ __forceinline__ int naddr32(int R, int c) {
    return R * 128 + (((c + R + (R >> 1)) & 7) << 4);
}
static __device__ __forceinline__ void store_h32(char* smem, int R, int col, float v) {
    *(float*)(smem + naddr32(R, col >> 2) + (col & 3) * 4) = v;
}

// ---------------------------------------------------------------------------
// bprep: symmetric-pair B table (K=2144 -> 67 ksteps), MFMA-fragment order.
// Separate kernel: its output crosses blocks; kernel boundary = coherence.
// ---------------------------------------------------------------------------
__global__ __launch_bounds__(64) void bprep_kernel(
    const float* __restrict__ V, const float* __restrict__ W,
    unsigned short* __restrict__ B)
{
    int t = blockIdx.x * 64 + threadIdx.x;
    if (t >= 8576) return;                   // 67*2*64
    int ks = t >> 7, sub = t & 127;
    int n = sub >> 6, lane = sub & 63;
    int hi = lane >> 4, l15 = lane & 15;
    int k = n * 16 + l15;
    const float* Vk = V + (size_t)k * 4096;
    ushort8v o;
    #pragma unroll
    for (int i = 0; i < 8; ++i) {
        int r5 = hi * 8 + i;
        float val;
        if (ks < 2)        { int j = 32 * ks + r5; val = Vk[j * 64 + j]; }
        else if (ks < 64)  { int d = ks >> 1; int j = 32 * (ks & 1) + r5; int l = (j + d) & 63;
                             val = Vk[j * 64 + l] + Vk[l * 64 + j]; }
        else if (ks == 64) { int j = r5; val = Vk[j * 64 + j + 32] + Vk[(j + 32) * 64 + j]; }
        else               { int j = (ks == 65) ? r5 : (32 + r5); val = W[j * 32 + k]; }
        o[i] = f2bf(val);
    }
    *(ushort8v*)(B + (size_t)t * 8) = o;
}

// ---------------------------------------------------------------------------
// crot[x] = c[(x + hi*8) & 63], fp32, from rotated-chunk LDS rows Rc, Rc+1.
// ---------------------------------------------------------------------------
static __device__ __forceinline__ void load_crot32(
    const char* nodes, int Rc, int hi, float* crot)
{
    #pragma unroll
    for (int t = 0; t < 16; ++t) {
        int m = (hi * 2 + t) & 15;           // chunk in 64-float c-space
        int row = Rc + (m >> 3), c4 = m & 7;
        f32x4 v = *(const f32x4*)(nodes + naddr32(row, c4));
        #pragma unroll
        for (int e = 0; e < 4; ++e) crot[t * 4 + e] = v[e];
    }
}

// ---------------------------------------------------------------------------
// Compile-time k-range, BOTH ntiles per wave (one A-build -> 2 MFMAs).
// ---------------------------------------------------------------------------
template<int K0, int K1>
static __device__ __forceinline__ void run2_k(
    const unsigned short* __restrict__ Bg, const float* crot,
    int lane, f32x4& a0, f32x4& a1)
{
    const char* bp = (const char*)Bg + lane * 16;
    #pragma unroll
    for (int ks = K0; ks < K1; ++ks) {
        uint4v aw;
        #pragma unroll
        for (int q = 0; q < 4; ++q) {
            int i0 = 2 * q, i1 = 2 * q + 1;
            float p0, p1;
            if (ks < 2)       { p0 = crot[32*ks+i0] * crot[32*ks+i0];
                                p1 = crot[32*ks+i1] * crot[32*ks+i1]; }
            else if (ks < 64) { const int bse = 32 * (ks & 1), d = ks >> 1;
                                p0 = crot[bse+i0] * crot[(bse+i0+d)&63];
                                p1 = crot[bse+i1] * crot[(bse+i1+d)&63]; }
            else if (ks == 64){ p0 = crot[i0] * crot[32+i0];
                                p1 = crot[i1] * crot[32+i1]; }
            else if (ks == 65){ p0 = crot[i0];    p1 = crot[i1]; }
            else              { p0 = crot[32+i0]; p1 = crot[32+i1]; }
            unsigned int pk;
            asm("v_cvt_pk_bf16_f32 %0, %1, %2" : "=v"(pk) : "v"(p0), "v"(p1));
            aw[q] = pk;
        }
        bf16x8 afr = __builtin_bit_cast(bf16x8, aw);
        bf16x8 b0 = *(const bf16x8*)(bp + (ks << 11));
        bf16x8 b1 = *(const bf16x8*)(bp + (ks << 11) + 1024);
        a0 = __builtin_amdgcn_mfma_f32_16x16x32_bf16(afr, b0, a0, 0, 0, 0);
        a1 = __builtin_amdgcn_mfma_f32_16x16x32_bf16(afr, b1, a1, 0, 0, 0);
    }
}

// log_softmax from 32 fp32 h values in rotated LDS row R -> out[g*5..]
static __device__ __forceinline__ void node_logits32(
    const char* smem, int R, const float* __restrict__ Wout_w,
    const float* __restrict__ Wout_b, float* __restrict__ out, size_t g)
{
    float h[32];
    #pragma unroll
    for (int c = 0; c < 8; ++c) {
        f32x4 v = *(const f32x4*)(smem + naddr32(R, c));
        #pragma unroll
        for (int e = 0; e < 4; ++e) h[c * 4 + e] = v[e];
    }
    float lg[OUT_N];
    #pragma unroll
    for (int o = 0; o < OUT_N; ++o) {
        const float* w = Wout_w + o * 32;
        float s = 0.f;
        #pragma unroll
        for (int x = 0; x < 32; ++x) s = fmaf(w[x], h[x], s);
        lg[o] = s + Wout_b[o];
    }
    float m = lg[0];
    #pragma unroll
    for (int o = 1; o < OUT_N; ++o) m = fmaxf(m, lg[o]);
    float sum = 0.f;
    #pragma unroll
    for (int o = 0; o < OUT_N; ++o) sum += expf(lg[o] - m);
    float lse = m + logf(sum);
    #pragma unroll
    for (int o = 0; o < OUT_N; ++o) out[g * OUT_N + o] = lg[o] - lse;
}

// ---------------------------------------------------------------------------
// One level tile: 4 waves = splitK4, both ntiles per wave. RPT = valid rows.
// childb/outb are runtime row bases (keeps template instantiations at 3).
// ---------------------------------------------------------------------------
constexpr int SCR = 12288;   // scratch base (3 slots x 2 KB)

template<int RPT, bool ROOT>
static __device__ __forceinline__ void level_run(
    char* smem, const unsigned short* __restrict__ Bg,
    const float* __restrict__ bias, float* __restrict__ roots,
    int bid, int lane, int u, int childb, int outb)
{
    const int l15 = lane & 15, hi = lane >> 4;
    int rc = (RPT >= 16) ? l15 : ((l15 < RPT) ? l15 : 0);
    float crot[64];
    load_crot32(smem, childb + 2 * rc, hi, crot);

    f32x4 a0 = {0.f,0.f,0.f,0.f}, a1 = {0.f,0.f,0.f,0.f};
    switch (u) {
        case 0:  run2_k< 0, 17>(Bg, crot, lane, a0, a1); break;
        case 1:  run2_k<17, 34>(Bg, crot, lane, a0, a1); break;
        case 2:  run2_k<34, 50>(Bg, crot, lane, a0, a1); break;
        default: run2_k<50, 67>(Bg, crot, lane, a0, a1); break;
    }
    if (u > 0) {
        char* sp = smem + SCR + (u - 1) * 2048 + lane * 32;
        *(f32x4*)sp = a0; *((f32x4*)sp + 1) = a1;
    }
    __syncthreads();
    if (u == 0) {
        #pragma unroll
        for (int v2 = 0; v2 < 3; ++v2) {
            const char* sp = smem + SCR + v2 * 2048 + lane * 32;
            a0 += *(const f32x4*)sp;
            a1 += *((const f32x4*)sp + 1);
        }
        float bk0 = bias[l15], bk1 = bias[16 + l15];
        #pragma unroll
        for (int r4 = 0; r4 < 4; ++r4) {
            int row = hi * 4 + r4;
            if (row < RPT) {
                float h0 = tanhf(a0[r4] + bk0), h1v = tanhf(a1[r4] + bk1);
                store_h32(smem, outb + row, l15, h0);
                store_h32(smem, outb + row, 16 + l15, h1v);
                if (ROOT) {
                    roots[(size_t)bid * 32 + l15]      = h0;
                    roots[(size_t)bid * 32 + 16 + l15] = h1v;
                }
            }
        }
    }
    __syncthreads();
}

// ---------------------------------------------------------------------------
// Fused tree kernel: block = ONE tree (512 blocks x 256 thr, 2 blocks/CU).
// __launch_bounds__(256, 2): cap 256 VGPR — (256,4)'s combined 128-cap forced
// arch-VGPR to 64 and spilled crot[] (round-10: 95 MB FETCH / 145 MB WRITE).
// Phase 1: 2 L1 tiles (leaf gather + exact leaf logits + level1 -> LDS only).
// Phase 2: L2..L6 + all logits + roots. h1 NEVER touches global memory.
// LDS rows: nodes 0..62 (h1 0..31, L2 32..47, L3 48..55, L4 56..59,
// L5 60..61, L6 62), leaf staging 64..95. Scratch 3x2KB @12288.
// ---------------------------------------------------------------------------
__global__ __launch_bounds__(256, 2) void tree_kernel(
    const int* __restrict__ word_ids, const float* __restrict__ embed,
    const unsigned short* __restrict__ Bg, const float* __restrict__ bias,
    const float* __restrict__ Wout_w, const float* __restrict__ Wout_b,
    float* __restrict__ out)
{
    __shared__ char smem[12288 + 6144];
    const int tid = threadIdx.x, lane = tid & 63;
    const int u = tid >> 6;
    const int bid = blockIdx.x;
    float* roots = out + ROOTS_OFF;

    // ---- phase 1: two 16-node L1 tiles (NOT unrolled: code-size/pressure) --
    #pragma unroll 1
    for (int p = 0; p < 2; ++p) {
        {   // stage 32 leaf rows fp32 + exact leaf logits
            int rr = tid >> 3, q4 = tid & 7;       // 32 rows x 8 chunks
            int leaf = (bid * 2 + p) * 32 + rr;
            int wid = word_ids[leaf];
            f32x4 v = ((const f32x4*)(embed + (size_t)wid * 32))[q4];
            *(f32x4*)(smem + naddr32(64 + rr, q4)) = v;

            float lg[OUT_N];
            #pragma unroll
            for (int o = 0; o < OUT_N; ++o) {
                const float* w = Wout_w + o * 32 + q4 * 4;
                lg[o] = w[0]*v[0] + w[1]*v[1] + w[2]*v[2] + w[3]*v[3];
            }
            #pragma unroll
            for (int o = 0; o < OUT_N; ++o) {
                lg[o] += __shfl_xor(lg[o], 1, 64);
                lg[o] += __shfl_xor(lg[o], 2, 64);
                lg[o] += __shfl_xor(lg[o], 4, 64);
            }
            if (q4 == 0) {
                #pragma unroll
                for (int o = 0; o < OUT_N; ++o) lg[o] += Wout_b[o];
                float m = lg[0];
                #pragma unroll
                for (int o = 1; o < OUT_N; ++o) m = fmaxf(m, lg[o]);
                float sum = 0.f;
                #pragma unroll
                for (int o = 0; o < OUT_N; ++o) sum += expf(lg[o] - m);
                float lse = m + logf(sum);
                #pragma unroll
                for (int o = 0; o < OUT_N; ++o) out[(size_t)leaf * OUT_N + o] = lg[o] - lse;
            }
        }
        __syncthreads();
        level_run<16, false>(smem, Bg, bias, roots, bid, lane, u, 64, p * 16);
    }

    // ---- h1 logits (rows 0..31 complete after level_run's trailing sync) --
    if (tid < 32)
        node_logits32(smem, tid, Wout_w, Wout_b, out,
                      (size_t)32768 + (size_t)bid * 32 + tid);

    // ---- phase 2: L2..L6 (children rows -> output rows, all in LDS) -------
    level_run<16, false>(smem, Bg, bias, roots, bid, lane, u,  0, 32);  // L2
    level_run< 8, false>(smem, Bg, bias, roots, bid, lane, u, 32, 48);  // L3
    level_run< 4, false>(smem, Bg, bias, roots, bid, lane, u, 48, 56);  // L4
    level_run< 2, false>(smem, Bg, bias, roots, bid, lane, u, 56, 60);  // L5
    level_run< 1, true >(smem, Bg, bias, roots, bid, lane, u, 60, 62);  // L6

    // ---- logits for the tree's 31 internal L2..L6 nodes -------------------
    if (tid < 31) {
        int rr = tid; int R; size_t g;
        if (rr < 16)      { R = 32 + rr;        g = 49152 + (size_t)bid * 16 + rr; }
        else if (rr < 24) { R = 48 + (rr - 16); g = 57344 + (size_t)bid * 8  + (rr - 16); }
        else if (rr < 28) { R = 56 + (rr - 24); g = 61440 + (size_t)bid * 4  + (rr - 24); }
        else if (rr < 30) { R = 60 + (rr - 28); g = 63488 + (size_t)bid * 2  + (rr - 28); }
        else              { R = 62;             g = 64512 + (size_t)bid; }
        node_logits32(smem, R, Wout_w, Wout_b, out, g);
    }
}

// ---------------------------------------------------------------------------
extern "C" void kernel_launch(void* const* d_in, const int* in_sizes, int n_in,
                              void* d_out, int out_size, void* d_ws, size_t ws_size,
                              hipStream_t stream)
{
    const int*   word_ids = (const int*)  d_in[0];
    const float* embed    = (const float*)d_in[1];
    const float* V        = (const float*)d_in[2];
    const float* W        = (const float*)d_in[3];
    const float* bvec     = (const float*)d_in[4];
    const float* Wout_w   = (const float*)d_in[5];
    const float* Wout_b   = (const float*)d_in[6];
    float* out = (float*)d_out;

    unsigned short* Bfrag = (unsigned short*)d_ws;   // 137,216 B

    bprep_kernel<<<134, 64, 0, stream>>>(V, W, Bfrag);
    tree_kernel<<<512, 256, 0, stream>>>(word_ids, embed, Bfrag, bvec,
                                         Wout_w, Wout_b, out);
}

// Round 12
// 39.001 us; speedup vs baseline: 3.4226x; 2.2201x over previous
//
#include <hip/hip_runtime.h>

#define OUT_N 5
#define TOTAL_NODES 65024
#define ROOTS_OFF (TOTAL_NODES * OUT_N)

typedef __attribute__((ext_vector_type(8))) short bf16x8;
typedef __attribute__((ext_vector_type(4))) float f32x4;
typedef __attribute__((ext_vector_type(8))) unsigned short ushort8v;
typedef __attribute__((ext_vector_type(4))) unsigned int uint4v;

static __device__ __forceinline__ unsigned short f2bf(float f) {
    union { float f; unsigned int i; } v; v.f = f;
    unsigned int r = v.i + 0x7fff + ((v.i >> 16) & 1);   // RNE
    return (unsigned short)(r >> 16);
}

// fp32 node row R (128 B), logical chunk c (0..7): physical chunk rotated by
// R + (R>>1) (odd coefficient in l15 -> spreads rows over all 8 rotations).
static __device__ __forceinline__ int naddr32(int R, int c) {
    return R * 128 + (((c + R + (R >> 1)) & 7) << 4);
}
static __device__ __forceinline__ void store_h32(char* smem, int R, int col, float v) {
    *(float*)(smem + naddr32(R, col >> 2) + (col & 3) * 4) = v;
}

// ---------------------------------------------------------------------------
// bprep: symmetric-pair B table (K=2144 -> 67 ksteps), MFMA-fragment order.
// ---------------------------------------------------------------------------
__global__ __launch_bounds__(64) void bprep_kernel(
    const float* __restrict__ V, const float* __restrict__ W,
    unsigned short* __restrict__ B)
{
    int t = blockIdx.x * 64 + threadIdx.x;
    if (t >= 8576) return;                   // 67*2*64
    int ks = t >> 7, sub = t & 127;
    int n = sub >> 6, lane = sub & 63;
    int hi = lane >> 4, l15 = lane & 15;
    int k = n * 16 + l15;
    const float* Vk = V + (size_t)k * 4096;
    ushort8v o;
    #pragma unroll
    for (int i = 0; i < 8; ++i) {
        int r5 = hi * 8 + i;
        float val;
        if (ks < 2)        { int j = 32 * ks + r5; val = Vk[j * 64 + j]; }
        else if (ks < 64)  { int d = ks >> 1; int j = 32 * (ks & 1) + r5; int l = (j + d) & 63;
                             val = Vk[j * 64 + l] + Vk[l * 64 + j]; }
        else if (ks == 64) { int j = r5; val = Vk[j * 64 + j + 32] + Vk[(j + 32) * 64 + j]; }
        else               { int j = (ks == 65) ? r5 : (32 + r5); val = W[j * 32 + k]; }
        o[i] = f2bf(val);
    }
    *(ushort8v*)(B + (size_t)t * 8) = o;
}

// ---------------------------------------------------------------------------
// crot[x] = c[(x + hi*8) & 63], fp32, from rotated-chunk LDS rows Rc, Rc+1.
// ---------------------------------------------------------------------------
static __device__ __forceinline__ void load_crot32(
    const char* nodes, int Rc, int hi, float* crot)
{
    #pragma unroll
    for (int t = 0; t < 16; ++t) {
        int m = (hi * 2 + t) & 15;           // chunk in 64-float c-space
        int row = Rc + (m >> 3), c4 = m & 7;
        f32x4 v = *(const f32x4*)(nodes + naddr32(row, c4));
        #pragma unroll
        for (int e = 0; e < 4; ++e) crot[t * 4 + e] = v[e];
    }
}

// ---------------------------------------------------------------------------
// Compile-time k-range, BOTH ntiles per wave (one A-build -> 2 MFMAs).
// ---------------------------------------------------------------------------
template<int K0, int K1>
static __device__ __forceinline__ void run2_k(
    const unsigned short* __restrict__ Bg, const float* crot,
    int lane, f32x4& a0, f32x4& a1)
{
    const char* bp = (const char*)Bg + lane * 16;
    #pragma unroll
    for (int ks = K0; ks < K1; ++ks) {
        uint4v aw;
        #pragma unroll
        for (int q = 0; q < 4; ++q) {
            int i0 = 2 * q, i1 = 2 * q + 1;
            float p0, p1;
            if (ks < 2)       { p0 = crot[32*ks+i0] * crot[32*ks+i0];
                                p1 = crot[32*ks+i1] * crot[32*ks+i1]; }
            else if (ks < 64) { const int bse = 32 * (ks & 1), d = ks >> 1;
                                p0 = crot[bse+i0] * crot[(bse+i0+d)&63];
                                p1 = crot[bse+i1] * crot[(bse+i1+d)&63]; }
            else if (ks == 64){ p0 = crot[i0] * crot[32+i0];
                                p1 = crot[i1] * crot[32+i1]; }
            else if (ks == 65){ p0 = crot[i0];    p1 = crot[i1]; }
            else              { p0 = crot[32+i0]; p1 = crot[32+i1]; }
            unsigned int pk;
            asm("v_cvt_pk_bf16_f32 %0, %1, %2" : "=v"(pk) : "v"(p0), "v"(p1));
            aw[q] = pk;
        }
        bf16x8 afr = __builtin_bit_cast(bf16x8, aw);
        bf16x8 b0 = *(const bf16x8*)(bp + (ks << 11));
        bf16x8 b1 = *(const bf16x8*)(bp + (ks << 11) + 1024);
        a0 = __builtin_amdgcn_mfma_f32_16x16x32_bf16(afr, b0, a0, 0, 0, 0);
        a1 = __builtin_amdgcn_mfma_f32_16x16x32_bf16(afr, b1, a1, 0, 0, 0);
    }
}

// log_softmax from 32 fp32 h values in rotated LDS row R -> out[g*5..]
static __device__ __forceinline__ void node_logits32(
    const char* smem, int R, const float* __restrict__ Wout_w,
    const float* __restrict__ Wout_b, float* __restrict__ out, size_t g)
{
    float h[32];
    #pragma unroll
    for (int c = 0; c < 8; ++c) {
        f32x4 v = *(const f32x4*)(smem + naddr32(R, c));
        #pragma unroll
        for (int e = 0; e < 4; ++e) h[c * 4 + e] = v[e];
    }
    float lg[OUT_N];
    #pragma unroll
    for (int o = 0; o < OUT_N; ++o) {
        const float* w = Wout_w + o * 32;
        float s = 0.f;
        #pragma unroll
        for (int x = 0; x < 32; ++x) s = fmaf(w[x], h[x], s);
        lg[o] = s + Wout_b[o];
    }
    float m = lg[0];
    #pragma unroll
    for (int o = 1; o < OUT_N; ++o) m = fmaxf(m, lg[o]);
    float sum = 0.f;
    #pragma unroll
    for (int o = 0; o < OUT_N; ++o) sum += expf(lg[o] - m);
    float lse = m + logf(sum);
    #pragma unroll
    for (int o = 0; o < OUT_N; ++o) out[g * OUT_N + o] = lg[o] - lse;
}

// ---------------------------------------------------------------------------
// ONE level tile (16 rows x 32 cols), 8 waves = splitK8, both ntiles/wave.
// __noinline__: single code copy (7 inlined copies were ~70 KB > 32 KB L1I
// and drove the round-10/11 crot[] spill). Runtime rpt/childb/outb/root.
// Scratch slots at lane*16 (b128-stride, conflict-free).
// ---------------------------------------------------------------------------
constexpr int SCR = 16384;   // scratch base (7 slots x 2 KB)

static __device__ __attribute__((noinline)) void level_run(
    char* smem, const unsigned short* __restrict__ Bg,
    const float* __restrict__ bias, float* __restrict__ roots,
    int bid, int tid, int rpt, int childb, int outb, bool root)
{
    const int lane = tid & 63, wave = tid >> 6;
    const int l15 = lane & 15, hi = lane >> 4;

    int rc = (l15 < rpt) ? l15 : 0;
    float crot[64];
    load_crot32(smem, childb + 2 * rc, hi, crot);

    f32x4 a0 = {0.f,0.f,0.f,0.f}, a1 = {0.f,0.f,0.f,0.f};
    switch (wave) {
        case 0:  run2_k< 0,  9>(Bg, crot, lane, a0, a1); break;
        case 1:  run2_k< 9, 17>(Bg, crot, lane, a0, a1); break;
        case 2:  run2_k<17, 26>(Bg, crot, lane, a0, a1); break;
        case 3:  run2_k<26, 34>(Bg, crot, lane, a0, a1); break;
        case 4:  run2_k<34, 42>(Bg, crot, lane, a0, a1); break;
        case 5:  run2_k<42, 50>(Bg, crot, lane, a0, a1); break;
        case 6:  run2_k<50, 59>(Bg, crot, lane, a0, a1); break;
        default: run2_k<59, 67>(Bg, crot, lane, a0, a1); break;
    }
    if (wave > 0) {
        char* sp = smem + SCR + (wave - 1) * 2048 + lane * 16;
        *(f32x4*)sp = a0;
        *(f32x4*)(sp + 1024) = a1;
    }
    __syncthreads();
    if (wave == 0) {
        #pragma unroll
        for (int v2 = 0; v2 < 7; ++v2) {
            const char* sp = smem + SCR + v2 * 2048 + lane * 16;
            a0 += *(const f32x4*)sp;
            a1 += *(const f32x4*)(sp + 1024);
        }
        float bk0 = bias[l15], bk1 = bias[16 + l15];
        #pragma unroll
        for (int r4 = 0; r4 < 4; ++r4) {
            int row = hi * 4 + r4;
            if (row < rpt) {
                float h0 = tanhf(a0[r4] + bk0), h1v = tanhf(a1[r4] + bk1);
                store_h32(smem, outb + row, l15, h0);
                store_h32(smem, outb + row, 16 + l15, h1v);
                if (root) {
                    roots[(size_t)bid * 32 + l15]      = h0;
                    roots[(size_t)bid * 32 + 16 + l15] = h1v;
                }
            }
        }
    }
    __syncthreads();
}

// ---------------------------------------------------------------------------
// Fused tree kernel: block = ONE tree, 512 thr (8 waves), 512 blocks (2/CU).
// (512,2) is the empirically no-spill shape (rounds 6/7/9: VGPR 116).
// LDS rows: nodes 0..62 (h1 0..31, L2 32..47, L3 48..55, L4 56..59,
// L5 60..61, L6 62), leaf staging 64..127. Scratch 7x2KB @16384.
// ---------------------------------------------------------------------------
__global__ __launch_bounds__(512, 2) void tree_kernel(
    const int* __restrict__ word_ids, const float* __restrict__ embed,
    const unsigned short* __restrict__ Bg, const float* __restrict__ bias,
    const float* __restrict__ Wout_w, const float* __restrict__ Wout_b,
    float* __restrict__ out)
{
    __shared__ char smem[16384 + 14336];
    const int tid = threadIdx.x;
    const int bid = blockIdx.x;
    float* roots = out + ROOTS_OFF;

    // ---- stage 64 leaf rows fp32 + exact leaf logits (512 thr = 64x8) -----
    {
        int rr = tid >> 3, q4 = tid & 7;
        int leaf = bid * 64 + rr;
        int wid = word_ids[leaf];
        f32x4 v = ((const f32x4*)(embed + (size_t)wid * 32))[q4];
        *(f32x4*)(smem + naddr32(64 + rr, q4)) = v;

        float lg[OUT_N];
        #pragma unroll
        for (int o = 0; o < OUT_N; ++o) {
            const float* w = Wout_w + o * 32 + q4 * 4;
            lg[o] = w[0]*v[0] + w[1]*v[1] + w[2]*v[2] + w[3]*v[3];
        }
        #pragma unroll
        for (int o = 0; o < OUT_N; ++o) {
            lg[o] += __shfl_xor(lg[o], 1, 64);
            lg[o] += __shfl_xor(lg[o], 2, 64);
            lg[o] += __shfl_xor(lg[o], 4, 64);
        }
        if (q4 == 0) {
            #pragma unroll
            for (int o = 0; o < OUT_N; ++o) lg[o] += Wout_b[o];
            float m = lg[0];
            #pragma unroll
            for (int o = 1; o < OUT_N; ++o) m = fmaxf(m, lg[o]);
            float sum = 0.f;
            #pragma unroll
            for (int o = 0; o < OUT_N; ++o) sum += expf(lg[o] - m);
            float lse = m + logf(sum);
            #pragma unroll
            for (int o = 0; o < OUT_N; ++o) out[(size_t)leaf * OUT_N + o] = lg[o] - lse;
        }
    }
    __syncthreads();

    // ---- 7 level tiles, all through the single level_run body -------------
    level_run(smem, Bg, bias, roots, bid, tid, 16, 64,  0, false);  // L1 lo
    level_run(smem, Bg, bias, roots, bid, tid, 16, 96, 16, false);  // L1 hi
    level_run(smem, Bg, bias, roots, bid, tid, 16,  0, 32, false);  // L2
    level_run(smem, Bg, bias, roots, bid, tid,  8, 32, 48, false);  // L3
    level_run(smem, Bg, bias, roots, bid, tid,  4, 48, 56, false);  // L4
    level_run(smem, Bg, bias, roots, bid, tid,  2, 56, 60, false);  // L5
    level_run(smem, Bg, bias, roots, bid, tid,  1, 60, 62, true);   // L6

    // ---- logits for the tree's 63 internal nodes --------------------------
    if (tid < 63) {
        int R = tid; size_t g;
        if (R < 32)      g = 32768 + (size_t)bid * 32 + R;
        else if (R < 48) g = 49152 + (size_t)bid * 16 + (R - 32);
        else if (R < 56) g = 57344 + (size_t)bid * 8  + (R - 48);
        else if (R < 60) g = 61440 + (size_t)bid * 4  + (R - 56);
        else if (R < 62) g = 63488 + (size_t)bid * 2  + (R - 60);
        else             g = 64512 + (size_t)bid;
        node_logits32(smem, R, Wout_w, Wout_b, out, g);
    }
}

// ---------------------------------------------------------------------------
extern "C" void kernel_launch(void* const* d_in, const int* in_sizes, int n_in,
                              void* d_out, int out_size, void* d_ws, size_t ws_size,
                              hipStream_t stream)
{
    const int*   word_ids = (const int*)  d_in[0];
    const float* embed    = (const float*)d_in[1];
    const float* V        = (const float*)d_in[2];
    const float* W        = (const float*)d_in[3];
    const float* bvec     = (const float*)d_in[4];
    const float* Wout_w   = (const float*)d_in[5];
    const float* Wout_b   = (const float*)d_in[6];
    float* out = (float*)d_out;

    unsigned short* Bfrag = (unsigned short*)d_ws;   // 137,216 B

    bprep_kernel<<<134, 64, 0, stream>>>(V, W, Bfrag);
    tree_kernel<<<512, 512, 0, stream>>>(word_ids, embed, Bfrag, bvec,
                                         Wout_w, Wout_b, out);
}

// Round 13
// 31.152 us; speedup vs baseline: 4.2850x; 1.2520x over previous
//
#include <hip/hip_runtime.h>

#define OUT_N 5
#define TOTAL_NODES 65024
#define ROOTS_OFF (TOTAL_NODES * OUT_N)

typedef __attribute__((ext_vector_type(8))) short bf16x8;
typedef __attribute__((ext_vector_type(4))) float f32x4;
typedef __attribute__((ext_vector_type(8))) unsigned short ushort8v;
typedef __attribute__((ext_vector_type(4))) unsigned int uint4v;

constexpr int B_BYTES   = 137216;                 // 67*2*64*16
constexpr int NODE_SZ   = 16128;                  // 126 rows * 128 B
constexpr int LEAF_SZ   = 8192;                   // 128 rows * 64 B (bf16)
constexpr int LDS_BIG   = B_BYTES + NODE_SZ + LEAF_SZ;   // 161536
constexpr int LDS_SMALL = NODE_SZ + LEAF_SZ;             // 24320

static __device__ __forceinline__ float bf2f(unsigned short u) {
    union { unsigned int i; float f; } v; v.i = ((unsigned int)u) << 16; return v.f;
}
static __device__ __forceinline__ unsigned short f2bf(float f) {
    union { float f; unsigned int i; } v; v.f = f;
    unsigned int r = v.i + 0x7fff + ((v.i >> 16) & 1);   // RNE
    return (unsigned short)(r >> 16);
}

// fp32 internal row R (128 B): chunk rotated by R+(R>>1) (odd l15 coeff ->
// 2-way max bank aliasing on crot reads; m136: 2-way is free).
static __device__ __forceinline__ int naddr32(int R, int c) {
    return R * 128 + (((c + R + (R >> 1)) & 7) << 4);
}
// bf16 leaf row R (64 B): 16B chunk rotated the same way (4 chunks).
static __device__ __forceinline__ int laddr16(int R, int q) {
    return R * 64 + (((q + R + (R >> 1)) & 3) << 4);
}
static __device__ __forceinline__ void store_h32(char* base, int R, int col, float v) {
    *(float*)(base + naddr32(R, col >> 2) + (col & 3) * 4) = v;
}
static __device__ __forceinline__ void load_crot32(
    const char* base, int Rc, int hi, float* crot)
{
    #pragma unroll
    for (int t = 0; t < 16; ++t) {
        int m = (hi * 2 + t) & 15;
        f32x4 v = *(const f32x4*)(base + naddr32(Rc + (m >> 3), m & 7));
        #pragma unroll
        for (int e = 0; e < 4; ++e) crot[t * 4 + e] = v[e];
    }
}

// ---------------------------------------------------------------------------
// bprep: symmetric-pair B table (K=2144 -> 67 ksteps), MFMA-fragment order.
// ---------------------------------------------------------------------------
__global__ __launch_bounds__(64) void bprep_kernel(
    const float* __restrict__ V, const float* __restrict__ W,
    unsigned short* __restrict__ B)
{
    int t = blockIdx.x * 64 + threadIdx.x;
    if (t >= 8576) return;                   // 67*2*64
    int ks = t >> 7, sub = t & 127;
    int n = sub >> 6, lane = sub & 63;
    int hi = lane >> 4, l15 = lane & 15;
    int k = n * 16 + l15;
    const float* Vk = V + (size_t)k * 4096;
    ushort8v o;
    #pragma unroll
    for (int i = 0; i < 8; ++i) {
        int r5 = hi * 8 + i;
        float val;
        if (ks < 2)        { int j = 32 * ks + r5; val = Vk[j * 64 + j]; }
        else if (ks < 64)  { int d = ks >> 1; int j = 32 * (ks & 1) + r5; int l = (j + d) & 63;
                             val = Vk[j * 64 + l] + Vk[l * 64 + j]; }
        else if (ks == 64) { int j = r5; val = Vk[j * 64 + j + 32] + Vk[(j + 32) * 64 + j]; }
        else               { int j = (ks == 65) ? r5 : (32 + r5); val = W[j * 32 + k]; }
        o[i] = f2bf(val);
    }
    *(ushort8v*)(B + (size_t)t * 8) = o;
}

// ---------------------------------------------------------------------------
// Single-ntile K-range: A built in fp32 from crot (compile-time indices),
// B from LDS (BLDS=1, ds_read via extern __shared__) or global (fallback).
// ---------------------------------------------------------------------------
template<int BLDS, int K0, int K1>
static __device__ __forceinline__ f32x4 run1(
    const unsigned short* __restrict__ Bg, const float* crot,
    int lane, int n, f32x4 acc)
{
    extern __shared__ char smem[];
    const int lo = lane * 16 + (n << 10);
    #pragma unroll
    for (int ks = K0; ks < K1; ++ks) {
        uint4v aw;
        #pragma unroll
        for (int q = 0; q < 4; ++q) {
            int i0 = 2 * q, i1 = 2 * q + 1;
            float p0, p1;
            if (ks < 2)       { p0 = crot[32*ks+i0] * crot[32*ks+i0];
                                p1 = crot[32*ks+i1] * crot[32*ks+i1]; }
            else if (ks < 64) { const int bse = 32 * (ks & 1), d = ks >> 1;
                                p0 = crot[bse+i0] * crot[(bse+i0+d)&63];
                                p1 = crot[bse+i1] * crot[(bse+i1+d)&63]; }
            else if (ks == 64){ p0 = crot[i0] * crot[32+i0];
                                p1 = crot[i1] * crot[32+i1]; }
            else if (ks == 65){ p0 = crot[i0];    p1 = crot[i1]; }
            else              { p0 = crot[32+i0]; p1 = crot[32+i1]; }
            unsigned int pk;
            asm("v_cvt_pk_bf16_f32 %0, %1, %2" : "=v"(pk) : "v"(p0), "v"(p1));
            aw[q] = pk;
        }
        bf16x8 afr = __builtin_bit_cast(bf16x8, aw);
        bf16x8 b;
        if constexpr (BLDS) b = *(const bf16x8*)(smem + (ks << 11) + lo);
        else                b = *(const bf16x8*)((const char*)Bg + (ks << 11) + lo);
        acc = __builtin_amdgcn_mfma_f32_16x16x32_bf16(afr, b, acc, 0, 0, 0);
    }
    return acc;
}

// ---------------------------------------------------------------------------
// L1: 8 waves = 4 tiles x 2 ntiles, full K, NO reduction. bf16 leaf children.
// ---------------------------------------------------------------------------
template<int BLDS>
static __device__ __attribute__((noinline)) void worker_l1(
    const unsigned short* __restrict__ Bg, const float* __restrict__ bias, int tid)
{
    extern __shared__ char smem[];
    constexpr int NODE = BLDS ? B_BYTES : 0;
    constexpr int LEAF = NODE + NODE_SZ;
    const int lane = tid & 63, w = tid >> 6;
    const int l15 = lane & 15, hi = lane >> 4;
    const int tile = w >> 1, n = w & 1;
    const int tree = tile >> 1, half = tile & 1;

    const int Rc = tree * 64 + half * 32 + 2 * l15;   // leaf child-pair rows
    float crot[64];
    #pragma unroll
    for (int t = 0; t < 8; ++t) {
        int m = (hi + t) & 7;
        ushort8v v = *(const ushort8v*)(smem + LEAF + laddr16(Rc + (m >> 2), m & 3));
        #pragma unroll
        for (int e = 0; e < 8; ++e) crot[t * 8 + e] = bf2f(v[e]);
    }

    f32x4 a = {0.f,0.f,0.f,0.f};
    a = run1<BLDS, 0, 67>(Bg, crot, lane, n, a);

    float bk = bias[n * 16 + l15];
    #pragma unroll
    for (int r = 0; r < 4; ++r) {
        int R = tree * 63 + half * 16 + hi * 4 + r;
        store_h32(smem + NODE, R, n * 16 + l15, tanhf(a[r] + bk));
    }
    __syncthreads();
}

// ---------------------------------------------------------------------------
// L2: 8 waves = 2 trees x 2 ntiles x splitK2. fp32 h1 children.
// ---------------------------------------------------------------------------
template<int BLDS>
static __device__ __attribute__((noinline)) void worker_l2(
    const unsigned short* __restrict__ Bg, const float* __restrict__ bias, int tid)
{
    extern __shared__ char smem[];
    constexpr int NODE = BLDS ? B_BYTES : 0;
    constexpr int SCR  = NODE + NODE_SZ;     // aliases dead leaf region
    const int lane = tid & 63, w = tid >> 6;
    const int l15 = lane & 15, hi = lane >> 4;
    const int tree = w >> 2, n = (w >> 1) & 1, u = w & 1;

    float crot[64];
    load_crot32(smem + NODE, tree * 63 + 2 * l15, hi, crot);

    f32x4 a = {0.f,0.f,0.f,0.f};
    if (u == 0) a = run1<BLDS,  0, 34>(Bg, crot, lane, n, a);
    else        a = run1<BLDS, 34, 67>(Bg, crot, lane, n, a);

    if (u == 1) *(f32x4*)(smem + SCR + ((tree * 2 + n) << 10) + lane * 16) = a;
    __syncthreads();
    if (u == 0) {
        a += *(const f32x4*)(smem + SCR + ((tree * 2 + n) << 10) + lane * 16);
        float bk = bias[n * 16 + l15];
        #pragma unroll
        for (int r = 0; r < 4; ++r) {
            int R = tree * 63 + 32 + hi * 4 + r;
            store_h32(smem + NODE, R, n * 16 + l15, tanhf(a[r] + bk));
        }
    }
    __syncthreads();
}

// ---------------------------------------------------------------------------
// L3..L6: packed 2-tree tile, 8 waves = 2 ntiles x splitK4. s = log2(rows/tree).
// ---------------------------------------------------------------------------
template<int BLDS>
static __device__ __attribute__((noinline)) void worker_deep(
    const unsigned short* __restrict__ Bg, const float* __restrict__ bias,
    float* __restrict__ roots, int bid, int tid,
    int s, int childb, int outb, bool root)
{
    extern __shared__ char smem[];
    constexpr int NODE = BLDS ? B_BYTES : 0;
    constexpr int SCR  = NODE + NODE_SZ;
    const int lane = tid & 63, w = tid >> 6;
    const int l15 = lane & 15, hi = lane >> 4;
    const int n = w >> 2, u = w & 3;
    const int rptT = 1 << s, rows2 = 2 << s;

    int rc = (l15 < rows2) ? l15 : 0;
    int tree = rc >> s, i = rc & (rptT - 1);
    float crot[64];
    load_crot32(smem + NODE, tree * 63 + childb + 2 * i, hi, crot);

    f32x4 a = {0.f,0.f,0.f,0.f};
    switch (u) {
        case 0:  a = run1<BLDS,  0, 17>(Bg, crot, lane, n, a); break;
        case 1:  a = run1<BLDS, 17, 34>(Bg, crot, lane, n, a); break;
        case 2:  a = run1<BLDS, 34, 50>(Bg, crot, lane, n, a); break;
        default: a = run1<BLDS, 50, 67>(Bg, crot, lane, n, a); break;
    }
    if (u > 0) *(f32x4*)(smem + SCR + ((n * 3 + u - 1) << 10) + lane * 16) = a;
    __syncthreads();
    if (u == 0) {
        #pragma unroll
        for (int v2 = 0; v2 < 3; ++v2)
            a += *(const f32x4*)(smem + SCR + ((n * 3 + v2) << 10) + lane * 16);
        float bk = bias[n * 16 + l15];
        #pragma unroll
        for (int r = 0; r < 4; ++r) {
            int row = hi * 4 + r;
            if (row < rows2) {
                int t2 = row >> s, i2 = row & (rptT - 1);
                float h = tanhf(a[r] + bk);
                store_h32(smem + NODE, t2 * 63 + outb + i2, n * 16 + l15, h);
                if (root) roots[(size_t)(bid * 2 + t2) * 32 + n * 16 + l15] = h;
            }
        }
    }
    __syncthreads();
}

// log_softmax from fp32 internal LDS row -> out[g*5..]
static __device__ __forceinline__ void node_logits32(
    const char* nodebase, int R, const float* __restrict__ Wout_w,
    const float* __restrict__ Wout_b, float* __restrict__ out, size_t g)
{
    float h[32];
    #pragma unroll
    for (int c = 0; c < 8; ++c) {
        f32x4 v = *(const f32x4*)(nodebase + naddr32(R, c));
        #pragma unroll
        for (int e = 0; e < 4; ++e) h[c * 4 + e] = v[e];
    }
    float lg[OUT_N];
    #pragma unroll
    for (int o = 0; o < OUT_N; ++o) {
        const float* ww = Wout_w + o * 32;
        float s = 0.f;
        #pragma unroll
        for (int x = 0; x < 32; ++x) s = fmaf(ww[x], h[x], s);
        lg[o] = s + Wout_b[o];
    }
    float m = lg[0];
    #pragma unroll
    for (int o = 1; o < OUT_N; ++o) m = fmaxf(m, lg[o]);
    float sum = 0.f;
    #pragma unroll
    for (int o = 0; o < OUT_N; ++o) sum += expf(lg[o] - m);
    float lse = m + logf(sum);
    #pragma unroll
    for (int o = 0; o < OUT_N; ++o) out[g * OUT_N + o] = lg[o] - lse;
}

// ---------------------------------------------------------------------------
// Fused tree kernel: block = 2 trees, 256 blocks x 512 thr, 1 block/CU.
// BLDS=1: B staged to LDS once, all kstep reads are ds_read (L2-BW fix).
// ---------------------------------------------------------------------------
template<int BLDS>
__global__ __launch_bounds__(512, 2) void tree_kernel(
    const int* __restrict__ word_ids, const float* __restrict__ embed,
    const unsigned short* __restrict__ Bg, const float* __restrict__ bias,
    const float* __restrict__ Wout_w, const float* __restrict__ Wout_b,
    float* __restrict__ out)
{
    extern __shared__ char smem[];
    constexpr int NODE = BLDS ? B_BYTES : 0;
    constexpr int LEAF = NODE + NODE_SZ;
    const int tid = threadIdx.x, bid = blockIdx.x;
    float* roots = out + ROOTS_OFF;

    // ---- stage B into LDS (137 KB, coalesced 16B/thread) ------------------
    if constexpr (BLDS) {
        const ushort8v* src = (const ushort8v*)Bg;
        #pragma unroll
        for (int r2 = 0; r2 < 16; ++r2) {
            int idx = r2 * 512 + tid;
            *(ushort8v*)(smem + idx * 16) = src[idx];
        }
        int idx = 8192 + tid;
        if (idx < 8576) *(ushort8v*)(smem + idx * 16) = src[idx];
    }

    // ---- stage 128 leaf rows (bf16) + EXACT fp32 leaf logits --------------
    {
        int rr = tid >> 2, q4 = tid & 3;         // 4 thr/row, 8 floats each
        int leaf = bid * 128 + rr;
        int wid = word_ids[leaf];
        const f32x4* ep = (const f32x4*)(embed + (size_t)wid * 32) + q4 * 2;
        f32x4 v0 = ep[0], v1 = ep[1];
        ushort8v o;
        #pragma unroll
        for (int e = 0; e < 4; ++e) { o[e] = f2bf(v0[e]); o[4 + e] = f2bf(v1[e]); }
        *(ushort8v*)(smem + LEAF + laddr16(rr, q4)) = o;

        float lg[OUT_N];
        #pragma unroll
        for (int o5 = 0; o5 < OUT_N; ++o5) {
            const float* ww = Wout_w + o5 * 32 + q4 * 8;
            lg[o5] = ww[0]*v0[0] + ww[1]*v0[1] + ww[2]*v0[2] + ww[3]*v0[3]
                   + ww[4]*v1[0] + ww[5]*v1[1] + ww[6]*v1[2] + ww[7]*v1[3];
        }
        #pragma unroll
        for (int o5 = 0; o5 < OUT_N; ++o5) {
            lg[o5] += __shfl_xor(lg[o5], 1, 64);
            lg[o5] += __shfl_xor(lg[o5], 2, 64);
        }
        if (q4 == 0) {
            #pragma unroll
            for (int o5 = 0; o5 < OUT_N; ++o5) lg[o5] += Wout_b[o5];
            float m = lg[0];
            #pragma unroll
            for (int o5 = 1; o5 < OUT_N; ++o5) m = fmaxf(m, lg[o5]);
            float sum = 0.f;
            #pragma unroll
            for (int o5 = 0; o5 < OUT_N; ++o5) sum += expf(lg[o5] - m);
            float lse = m + logf(sum);
            #pragma unroll
            for (int o5 = 0; o5 < OUT_N; ++o5)
                out[(size_t)leaf * OUT_N + o5] = lg[o5] - lse;
        }
    }
    __syncthreads();

    // ---- 6 levels ---------------------------------------------------------
    worker_l1<BLDS>(Bg, bias, tid);
    worker_l2<BLDS>(Bg, bias, tid);
    worker_deep<BLDS>(Bg, bias, roots, bid, tid, 3, 32, 48, false);  // L3
    worker_deep<BLDS>(Bg, bias, roots, bid, tid, 2, 48, 56, false);  // L4
    worker_deep<BLDS>(Bg, bias, roots, bid, tid, 1, 56, 60, false);  // L5
    worker_deep<BLDS>(Bg, bias, roots, bid, tid, 0, 60, 62, true);   // L6

    // ---- logits for 126 internal rows (2 trees x 63) ----------------------
    if (tid < 126) {
        int tree = (tid >= 63) ? 1 : 0;
        int r = tid - 63 * tree;
        size_t tg = (size_t)bid * 2 + tree;
        int R = tree * 63 + r;
        size_t g;
        if (r < 32)      g = 32768 + tg * 32 + r;
        else if (r < 48) g = 49152 + tg * 16 + (r - 32);
        else if (r < 56) g = 57344 + tg * 8  + (r - 48);
        else if (r < 60) g = 61440 + tg * 4  + (r - 56);
        else if (r < 62) g = 63488 + tg * 2  + (r - 60);
        else             g = 64512 + tg;
        node_logits32(smem + NODE, R, Wout_w, Wout_b, out, g);
    }
}

// ---------------------------------------------------------------------------
extern "C" void kernel_launch(void* const* d_in, const int* in_sizes, int n_in,
                              void* d_out, int out_size, void* d_ws, size_t ws_size,
                              hipStream_t stream)
{
    const int*   word_ids = (const int*)  d_in[0];
    const float* embed    = (const float*)d_in[1];
    const float* V        = (const float*)d_in[2];
    const float* W        = (const float*)d_in[3];
    const float* bvec     = (const float*)d_in[4];
    const float* Wout_w   = (const float*)d_in[5];
    const float* Wout_b   = (const float*)d_in[6];
    float* out = (float*)d_out;

    unsigned short* Bfrag = (unsigned short*)d_ws;   // 137,216 B

    bprep_kernel<<<134, 64, 0, stream>>>(V, W, Bfrag);

    hipError_t e = hipFuncSetAttribute((const void*)&tree_kernel<1>,
                     hipFuncAttributeMaxDynamicSharedMemorySize, LDS_BIG);
    if (e == hipSuccess) {
        tree_kernel<1><<<256, 512, LDS_BIG, stream>>>(
            word_ids, embed, Bfrag, bvec, Wout_w, Wout_b, out);
    } else {
        tree_kernel<0><<<256, 512, LDS_SMALL, stream>>>(
            word_ids, embed, Bfrag, bvec, Wout_w, Wout_b, out);
    }
}